// Round 1
// baseline (1245.125 us; speedup 1.0000x reference)
//
#include <hip/hip_runtime.h>
#include <hip/hip_bf16.h>

#define N_BATCH 8
#define N_CH    16
#define N_SMP   480000
#define N_EARS  2
#define N_TAP   2048

#define NKT     65                    // K-tiles (of 32) per channel
#define ROWS    256                   // q-rows per block (4 waves x 4 msubs x 16)
#define N_QROWS (N_SMP / 16)          // 30000
#define QB_PER_B ((N_QROWS + ROWS - 1) / ROWS)   // 118
#define XS_LEN  6400                  // bf16 elems per buffer (6160 real + pad for dead refills)
#define NF4     (XS_LEN / 4)          // 1600 float4 staging slots
#define BLK     256

typedef __bf16 bf16x8 __attribute__((ext_vector_type(8)));
typedef float  f32x4  __attribute__((ext_vector_type(4)));

// ---------------------------------------------------------------------------
// Prep: pack filters into MFMA-B-fragment order (verified rounds 1-2).
// B[u][n] = h[e][c][2048 - u + n], u = kt*32 + (lane>>4)*8 + j, n = lane&15.
// Flat: (((c*NKT + kt)*2 + e)*64 + lane)*8 + j  -> 16B/lane, coalesced.
// ---------------------------------------------------------------------------
__global__ void build_bpk(const float* __restrict__ h, __bf16* __restrict__ bpk)
{
    const int idx = blockIdx.x * 256 + threadIdx.x;
    const int total = N_CH * NKT * 2 * 64 * 8;
    if (idx >= total) return;

    const int j    = idx & 7;
    const int lane = (idx >> 3) & 63;
    const int e    = (idx >> 9) & 1;
    const int ckt  = idx >> 10;          // c*NKT + kt
    const int kt   = ckt % NKT;
    const int c    = ckt / NKT;

    const int n  = lane & 15;
    const int kq = (lane >> 4) * 8 + j;
    const int u  = kt * 32 + kq;
    const int k  = 2048 - u + n;

    float val = (k >= 0 && k < N_TAP) ? h[((long)e * N_CH + c) * N_TAP + k] : 0.0f;
    bpk[idx] = (__bf16)val;
}

// ---------------------------------------------------------------------------
// Main GEMM. Occupancy-first restructure vs previous round:
//   * W[4][8] full-reuse window (128 VGPR) -> rolling queues Q[4][2] (32 VGPR,
//     4 ds_read_b128 per K-tile; ~105 B/cyc/CU at full MFMA rate, under LDS cap)
//   * persistent sreg[7] staging pipeline (28 VGPR live across K-loop) -> lazy
//     stage at channel end (transient regs only; latency covered by co-resident
//     blocks at 4 blocks/CU)
//   * BQ prime hoisted above the barrier (global loads, no LDS dependency)
//   * __launch_bounds__(BLK, 4): total VGPR+AGPR <= 128 -> 4 waves/SIMD.
// Math identical to the verified round-2 kernel: at K-tile kt, msub s consumes
// f(kt + 8s), f(j) = xs[abase + 32j]; queue slot parity kt&1, refill f(kt+2+8s).
// ---------------------------------------------------------------------------
__global__ __launch_bounds__(BLK, 4)
void hoa_bin_gemm(const float* __restrict__ hoa,
                  const __bf16* __restrict__ bpk,
                  float* __restrict__ out)
{
    __shared__ __align__(16) __bf16 xs[2][XS_LEN];

    const int qb   = blockIdx.x;          // 0..117
    const int b    = blockIdx.y;          // 0..7
    const int tid  = threadIdx.x;
    const int lane = tid & 63;
    const int wv   = tid >> 6;            // wave 0..3
    const int mlan = lane & 15;
    const int quad = lane >> 4;

    const int q0 = qb * ROWS;
    const int t0 = 16 * q0 - 2048;        // sample index of xs[.][0]

    const int abase = wv * 1024 + 16 * mlan + 8 * quad;

    const float* xb = hoa + (long)b * N_CH * N_SMP;

    f32x4 acc[4][2] = {};                 // [msub][ear]

    // ---- prologue: stage channel 0 into xs[0] (transient regs) ----
    {
        float4 v[7];
        #pragma unroll
        for (int k = 0; k < 7; ++k) {
            const int i4 = tid + k * BLK;
            const int t  = t0 + 4 * i4;
            float4 w = {0.f, 0.f, 0.f, 0.f};
            if (i4 < NF4 && t >= 0 && t <= N_SMP - 4) w = *(const float4*)(xb + t);
            v[k] = w;
        }
        #pragma unroll
        for (int k = 0; k < 7; ++k) {
            const int i4 = tid + k * BLK;
            if (i4 < NF4) {
                union { __bf16 hh[4]; uint2 u; } pk;
                pk.hh[0] = (__bf16)v[k].x; pk.hh[1] = (__bf16)v[k].y;
                pk.hh[2] = (__bf16)v[k].z; pk.hh[3] = (__bf16)v[k].w;
                *(uint2*)(&xs[0][4 * i4]) = pk.u;
            }
        }
    }

    for (int c = 0; c < N_CH; ++c) {
        const __bf16* bp = bpk + (long)c * (NKT * 1024) + lane * 8;

        // ---- prime B queue (depth 3) BEFORE barrier: L2 latency hides under
        //      the barrier wait; no LDS dependency ----
        bf16x8 BQ0[3], BQ1[3];
        #pragma unroll
        for (int d = 0; d < 3; ++d) {
            BQ0[d] = *(const bf16x8*)(bp + d * 1024);
            BQ1[d] = *(const bf16x8*)(bp + d * 1024 + 512);
        }

        __syncthreads();   // xs[c&1] fully staged by all waves

        const __bf16* xw = &xs[c & 1][0];

        // ---- prime A queues: Q[s][d] = f(d + 8s), d = 0,1 ----
        bf16x8 Q[4][2];
        #pragma unroll
        for (int s = 0; s < 4; ++s)
            #pragma unroll
            for (int d = 0; d < 2; ++d)
                Q[s][d] = *(const bf16x8*)(xw + abase + 32 * (d + 8 * s));

        // ---- K-loop: 64 tiles as 32 parity pairs, fully unrolled ----
        #pragma unroll
        for (int kp = 0; kp < 32; ++kp) {
            #pragma unroll
            for (int par = 0; par < 2; ++par) {
                const int kt = 2 * kp + par;
                const int d3 = kt % 3;
                bf16x8 b0 = BQ0[d3];
                bf16x8 b1 = BQ1[d3];
                const int ktp = (kt + 3 <= 64) ? kt + 3 : 64;   // compile-time
                BQ0[d3] = *(const bf16x8*)(bp + ktp * 1024);
                BQ1[d3] = *(const bf16x8*)(bp + ktp * 1024 + 512);
                #pragma unroll
                for (int s = 0; s < 4; ++s) {
                    acc[s][0] = __builtin_amdgcn_mfma_f32_16x16x32_bf16(
                                    Q[s][par], b0, acc[s][0], 0, 0, 0);
                    acc[s][1] = __builtin_amdgcn_mfma_f32_16x16x32_bf16(
                                    Q[s][par], b1, acc[s][1], 0, 0, 0);
                }
                // refill slot `par` with f(kt+2+8s); kt=63 refill is dead but
                // lands in pad (max idx 3336 + 32*89 + 7 = 6191 < 6400)
                const int jn = kt + 2;
                #pragma unroll
                for (int s = 0; s < 4; ++s)
                    Q[s][par] = *(const bf16x8*)(xw + abase + 32 * (jn + 8 * s));
            }
        }

        // ---- tail kt = 64: slot 64&1 = 0 holds f(64+8s); BQ slot 64%3 = 1 ----
        {
            bf16x8 b0 = BQ0[1];
            bf16x8 b1 = BQ1[1];
            #pragma unroll
            for (int s = 0; s < 4; ++s) {
                acc[s][0] = __builtin_amdgcn_mfma_f32_16x16x32_bf16(
                                Q[s][0], b0, acc[s][0], 0, 0, 0);
                acc[s][1] = __builtin_amdgcn_mfma_f32_16x16x32_bf16(
                                Q[s][0], b1, acc[s][1], 0, 0, 0);
            }
        }

        // ---- lazy stage channel c+1 into the other buffer (transient regs;
        //      exposed HBM latency covered by co-resident blocks) ----
        if (c + 1 < N_CH) {
            const float* xc = xb + (long)(c + 1) * N_SMP;
            float4 v[7];
            #pragma unroll
            for (int k = 0; k < 7; ++k) {
                const int i4 = tid + k * BLK;
                const int t  = t0 + 4 * i4;
                float4 w = {0.f, 0.f, 0.f, 0.f};
                if (i4 < NF4 && t >= 0 && t <= N_SMP - 4) w = *(const float4*)(xc + t);
                v[k] = w;
            }
            __bf16* xd = &xs[(c + 1) & 1][0];
            #pragma unroll
            for (int k = 0; k < 7; ++k) {
                const int i4 = tid + k * BLK;
                if (i4 < NF4) {
                    union { __bf16 hh[4]; uint2 u; } pk;
                    pk.hh[0] = (__bf16)v[k].x; pk.hh[1] = (__bf16)v[k].y;
                    pk.hh[2] = (__bf16)v[k].z; pk.hh[3] = (__bf16)v[k].w;
                    *(uint2*)(&xd[4 * i4]) = pk.u;
                }
            }
        }
    }

    // ---- epilogue: C/D layout row = quad*4 + r, col = lane&15 (verified) ----
    const long ob = (long)b * N_EARS * N_SMP;
    #pragma unroll
    for (int s = 0; s < 4; ++s) {
        #pragma unroll
        for (int e = 0; e < N_EARS; ++e) {
            #pragma unroll
            for (int r = 0; r < 4; ++r) {
                const int rl = wv * 64 + s * 16 + quad * 4 + r;
                const int q  = q0 + rl;
                if (q < N_QROWS)
                    out[ob + (long)e * N_SMP + 16 * q + mlan] = acc[s][e][r];
            }
        }
    }
}

// ---------------------------------------------------------------------------
extern "C" void kernel_launch(void* const* d_in, const int* in_sizes, int n_in,
                              void* d_out, int out_size, void* d_ws, size_t ws_size,
                              hipStream_t stream)
{
    const float* hoa = (const float*)d_in[0];   // [8,16,480000] fp32
    const float* h   = (const float*)d_in[1];   // [2,16,2048]  fp32
    float* out       = (float*)d_out;           // [8,2,480000] fp32
    __bf16* bpk      = (__bf16*)d_ws;           // 2,129,920 B filter pack

    const int total_bpk = N_CH * NKT * 2 * 64 * 8;          // 1,064,960
    build_bpk<<<(total_bpk + 255) / 256, 256, 0, stream>>>(h, bpk);

    dim3 grid(QB_PER_B, N_BATCH);
    hoa_bin_gemm<<<grid, BLK, 0, stream>>>(hoa, bpk, out);
}

// Round 2
// 998.486 us; speedup vs baseline: 1.2470x; 1.2470x over previous
//
#include <hip/hip_runtime.h>
#include <hip/hip_bf16.h>

#define N_BATCH 8
#define N_CH    16
#define N_SMP   480000
#define N_EARS  2
#define N_TAP   2048

#define NKT     65                    // K-tiles (of 32) per channel
#define ROWS    256                   // q-rows per block (4 waves x 4 msubs x 16)
#define N_QROWS (N_SMP / 16)          // 30000
#define QB_PER_B ((N_QROWS + ROWS - 1) / ROWS)   // 118
#define XS_LEN  6400                  // bf16 elems per buffer (6160 real + pad for dead refills)
#define NF4     (XS_LEN / 4)          // 1600 float4 staging slots
#define BLK     256

typedef __bf16 bf16x8 __attribute__((ext_vector_type(8)));
typedef float  f32x4  __attribute__((ext_vector_type(4)));

// ---------------------------------------------------------------------------
// Prep: pack filters into MFMA-B-fragment order (verified rounds 1-2).
// B[u][n] = h[e][c][2048 - u + n], u = kt*32 + (lane>>4)*8 + j, n = lane&15.
// Flat: (((c*NKT + kt)*2 + e)*64 + lane)*8 + j  -> 16B/lane, coalesced.
// ---------------------------------------------------------------------------
__global__ void build_bpk(const float* __restrict__ h, __bf16* __restrict__ bpk)
{
    const int idx = blockIdx.x * 256 + threadIdx.x;
    const int total = N_CH * NKT * 2 * 64 * 8;
    if (idx >= total) return;

    const int j    = idx & 7;
    const int lane = (idx >> 3) & 63;
    const int e    = (idx >> 9) & 1;
    const int ckt  = idx >> 10;          // c*NKT + kt
    const int kt   = ckt % NKT;
    const int c    = ckt / NKT;

    const int n  = lane & 15;
    const int kq = (lane >> 4) * 8 + j;
    const int u  = kt * 32 + kq;
    const int k  = 2048 - u + n;

    float val = (k >= 0 && k < N_TAP) ? h[((long)e * N_CH + c) * N_TAP + k] : 0.0f;
    bpk[idx] = (__bf16)val;
}

// ---------------------------------------------------------------------------
// Main GEMM. Round-2 lesson: __launch_bounds__(256,4) (128-reg budget) spills
// ~2.4 GB of scratch per dispatch (WRITE_SIZE 30MB -> 1.47GB). Steady-state
// demand of the rolling-Q loop is ~140 regs -> fits the 3-waves/EU budget
// (~170) with slack. 3 blocks/CU = 37.5% occupancy, no spills.
//   * rolling queues Q[4][2] (32 VGPR, 4 ds_read_b128/K-tile) instead of the
//     W[4][8] full-reuse window (128 VGPR) -> reg demand down ~90
//   * staging loads for channel c+1 issued at the K-loop midpoint (compile-
//     time placement in the unrolled loop): HBM latency hides under the
//     second-half MFMAs; the 28 staging regs live only across half the loop
//   * BQ prime hoisted above the barrier (global loads, no LDS dependency)
// Math identical to the verified round-2 kernel: at K-tile kt, msub s consumes
// f(kt + 8s), f(j) = xs[abase + 32j]; queue slot parity kt&1, refill f(kt+2+8s).
// ---------------------------------------------------------------------------
__global__ __launch_bounds__(BLK, 3)
void hoa_bin_gemm(const float* __restrict__ hoa,
                  const __bf16* __restrict__ bpk,
                  float* __restrict__ out)
{
    __shared__ __align__(16) __bf16 xs[2][XS_LEN];

    const int qb   = blockIdx.x;          // 0..117
    const int b    = blockIdx.y;          // 0..7
    const int tid  = threadIdx.x;
    const int lane = tid & 63;
    const int wv   = tid >> 6;            // wave 0..3
    const int mlan = lane & 15;
    const int quad = lane >> 4;

    const int q0 = qb * ROWS;
    const int t0 = 16 * q0 - 2048;        // sample index of xs[.][0]

    const int abase = wv * 1024 + 16 * mlan + 8 * quad;

    const float* xb = hoa + (long)b * N_CH * N_SMP;

    f32x4 acc[4][2] = {};                 // [msub][ear]

    // ---- prologue: stage channel 0 into xs[0] (transient regs) ----
    {
        float4 v[7];
        #pragma unroll
        for (int k = 0; k < 7; ++k) {
            const int i4 = tid + k * BLK;
            const int t  = t0 + 4 * i4;
            float4 w = {0.f, 0.f, 0.f, 0.f};
            if (i4 < NF4 && t >= 0 && t <= N_SMP - 4) w = *(const float4*)(xb + t);
            v[k] = w;
        }
        #pragma unroll
        for (int k = 0; k < 7; ++k) {
            const int i4 = tid + k * BLK;
            if (i4 < NF4) {
                union { __bf16 hh[4]; uint2 u; } pk;
                pk.hh[0] = (__bf16)v[k].x; pk.hh[1] = (__bf16)v[k].y;
                pk.hh[2] = (__bf16)v[k].z; pk.hh[3] = (__bf16)v[k].w;
                *(uint2*)(&xs[0][4 * i4]) = pk.u;
            }
        }
    }

    for (int c = 0; c < N_CH; ++c) {
        const __bf16* bp = bpk + (long)c * (NKT * 1024) + lane * 8;

        // ---- prime B queue (depth 3) BEFORE barrier: L2 latency hides under
        //      the barrier wait; no LDS dependency ----
        bf16x8 BQ0[3], BQ1[3];
        #pragma unroll
        for (int d = 0; d < 3; ++d) {
            BQ0[d] = *(const bf16x8*)(bp + d * 1024);
            BQ1[d] = *(const bf16x8*)(bp + d * 1024 + 512);
        }

        __syncthreads();   // xs[c&1] fully staged by all waves

        const __bf16* xw = &xs[c & 1][0];

        // ---- prime A queues: Q[s][d] = f(d + 8s), d = 0,1 ----
        bf16x8 Q[4][2];
        #pragma unroll
        for (int s = 0; s < 4; ++s)
            #pragma unroll
            for (int d = 0; d < 2; ++d)
                Q[s][d] = *(const bf16x8*)(xw + abase + 32 * (d + 8 * s));

        float4 sv[7];      // staging regs — live only from midpoint to loop end

        // ---- K-loop: 64 tiles as 32 parity pairs, fully unrolled, split in
        //      two halves with the staging-load issue at the midpoint ----
        #pragma unroll
        for (int kp = 0; kp < 16; ++kp) {
            #pragma unroll
            for (int par = 0; par < 2; ++par) {
                const int kt = 2 * kp + par;
                const int d3 = kt % 3;
                bf16x8 b0 = BQ0[d3];
                bf16x8 b1 = BQ1[d3];
                const int ktp = kt + 3;                     // <= 34, in range
                BQ0[d3] = *(const bf16x8*)(bp + ktp * 1024);
                BQ1[d3] = *(const bf16x8*)(bp + ktp * 1024 + 512);
                #pragma unroll
                for (int s = 0; s < 4; ++s) {
                    acc[s][0] = __builtin_amdgcn_mfma_f32_16x16x32_bf16(
                                    Q[s][par], b0, acc[s][0], 0, 0, 0);
                    acc[s][1] = __builtin_amdgcn_mfma_f32_16x16x32_bf16(
                                    Q[s][par], b1, acc[s][1], 0, 0, 0);
                }
                const int jn = kt + 2;
                #pragma unroll
                for (int s = 0; s < 4; ++s)
                    Q[s][par] = *(const bf16x8*)(xw + abase + 32 * (jn + 8 * s));
            }
        }

        // ---- midpoint: issue staging loads for channel c+1 (latency hides
        //      under the second-half MFMAs) ----
        if (c + 1 < N_CH) {
            const float* xc = xb + (long)(c + 1) * N_SMP;
            #pragma unroll
            for (int k = 0; k < 7; ++k) {
                const int i4 = tid + k * BLK;
                const int t  = t0 + 4 * i4;
                float4 w = {0.f, 0.f, 0.f, 0.f};
                if (i4 < NF4 && t >= 0 && t <= N_SMP - 4) w = *(const float4*)(xc + t);
                sv[k] = w;
            }
        }

        #pragma unroll
        for (int kp = 16; kp < 32; ++kp) {
            #pragma unroll
            for (int par = 0; par < 2; ++par) {
                const int kt = 2 * kp + par;
                const int d3 = kt % 3;
                bf16x8 b0 = BQ0[d3];
                bf16x8 b1 = BQ1[d3];
                const int ktp = (kt + 3 <= 64) ? kt + 3 : 64;   // compile-time
                BQ0[d3] = *(const bf16x8*)(bp + ktp * 1024);
                BQ1[d3] = *(const bf16x8*)(bp + ktp * 1024 + 512);
                #pragma unroll
                for (int s = 0; s < 4; ++s) {
                    acc[s][0] = __builtin_amdgcn_mfma_f32_16x16x32_bf16(
                                    Q[s][par], b0, acc[s][0], 0, 0, 0);
                    acc[s][1] = __builtin_amdgcn_mfma_f32_16x16x32_bf16(
                                    Q[s][par], b1, acc[s][1], 0, 0, 0);
                }
                // refill slot `par` with f(kt+2+8s); kt=63 refill is dead but
                // lands in pad (max idx 3320 + 32*89 + 7 = 6175 < 6400)
                const int jn = kt + 2;
                #pragma unroll
                for (int s = 0; s < 4; ++s)
                    Q[s][par] = *(const bf16x8*)(xw + abase + 32 * (jn + 8 * s));
            }
        }

        // ---- tail kt = 64: slot 64&1 = 0 holds f(64+8s); BQ slot 64%3 = 1 ----
        {
            bf16x8 b0 = BQ0[1];
            bf16x8 b1 = BQ1[1];
            #pragma unroll
            for (int s = 0; s < 4; ++s) {
                acc[s][0] = __builtin_amdgcn_mfma_f32_16x16x32_bf16(
                                Q[s][0], b0, acc[s][0], 0, 0, 0);
                acc[s][1] = __builtin_amdgcn_mfma_f32_16x16x32_bf16(
                                Q[s][0], b1, acc[s][1], 0, 0, 0);
            }
        }

        // ---- write staged channel c+1 into the other buffer ----
        if (c + 1 < N_CH) {
            __bf16* xd = &xs[(c + 1) & 1][0];
            #pragma unroll
            for (int k = 0; k < 7; ++k) {
                const int i4 = tid + k * BLK;
                if (i4 < NF4) {
                    union { __bf16 hh[4]; uint2 u; } pk;
                    pk.hh[0] = (__bf16)sv[k].x; pk.hh[1] = (__bf16)sv[k].y;
                    pk.hh[2] = (__bf16)sv[k].z; pk.hh[3] = (__bf16)sv[k].w;
                    *(uint2*)(&xd[4 * i4]) = pk.u;
                }
            }
        }
    }

    // ---- epilogue: C/D layout row = quad*4 + r, col = lane&15 (verified) ----
    const long ob = (long)b * N_EARS * N_SMP;
    #pragma unroll
    for (int s = 0; s < 4; ++s) {
        #pragma unroll
        for (int e = 0; e < N_EARS; ++e) {
            #pragma unroll
            for (int r = 0; r < 4; ++r) {
                const int rl = wv * 64 + s * 16 + quad * 4 + r;
                const int q  = q0 + rl;
                if (q < N_QROWS)
                    out[ob + (long)e * N_SMP + 16 * q + mlan] = acc[s][e][r];
            }
        }
    }
}

// ---------------------------------------------------------------------------
extern "C" void kernel_launch(void* const* d_in, const int* in_sizes, int n_in,
                              void* d_out, int out_size, void* d_ws, size_t ws_size,
                              hipStream_t stream)
{
    const float* hoa = (const float*)d_in[0];   // [8,16,480000] fp32
    const float* h   = (const float*)d_in[1];   // [2,16,2048]  fp32
    float* out       = (float*)d_out;           // [8,2,480000] fp32
    __bf16* bpk      = (__bf16*)d_ws;           // 2,129,920 B filter pack

    const int total_bpk = N_CH * NKT * 2 * 64 * 8;          // 1,064,960
    build_bpk<<<(total_bpk + 255) / 256, 256, 0, stream>>>(h, bpk);

    dim3 grid(QB_PER_B, N_BATCH);
    hoa_bin_gemm<<<grid, BLK, 0, stream>>>(hoa, bpk, out);
}

// Round 3
// 663.929 us; speedup vs baseline: 1.8754x; 1.5039x over previous
//
#include <hip/hip_runtime.h>
#include <hip/hip_bf16.h>

#define N_BATCH 8
#define N_CH    16
#define N_SMP   480000
#define N_EARS  2
#define N_TAP   2048

#define NKT     65                    // K-tiles (of 32) per channel
#define ROWS    256                   // q-rows per block (4 waves x 4 msubs x 16)
#define N_QROWS (N_SMP / 16)          // 30000
#define QB_PER_B ((N_QROWS + ROWS - 1) / ROWS)   // 118
#define XS_LEN  6400                  // bf16 elems per buffer (6160 real + pad for dead refills)
#define NF4     (XS_LEN / 4)          // 1600 float4 staging slots
#define BLK     256

typedef __bf16 bf16x8 __attribute__((ext_vector_type(8)));
typedef float  f32x4  __attribute__((ext_vector_type(4)));

// ---------------------------------------------------------------------------
// Prep: pack filters into MFMA-B-fragment order (verified rounds 1-2).
// B[u][n] = h[e][c][2048 - u + n], u = kt*32 + (lane>>4)*8 + j, n = lane&15.
// Flat: (((c*NKT + kt)*2 + e)*64 + lane)*8 + j  -> 16B/lane, coalesced.
// ---------------------------------------------------------------------------
__global__ void build_bpk(const float* __restrict__ h, __bf16* __restrict__ bpk)
{
    const int idx = blockIdx.x * 256 + threadIdx.x;
    const int total = N_CH * NKT * 2 * 64 * 8;
    if (idx >= total) return;

    const int j    = idx & 7;
    const int lane = (idx >> 3) & 63;
    const int e    = (idx >> 9) & 1;
    const int ckt  = idx >> 10;          // c*NKT + kt
    const int kt   = ckt % NKT;
    const int c    = ckt / NKT;

    const int n  = lane & 15;
    const int kq = (lane >> 4) * 8 + j;
    const int u  = kt * 32 + kq;
    const int k  = 2048 - u + n;

    float val = (k >= 0 && k < N_TAP) ? h[((long)e * N_CH + c) * N_TAP + k] : 0.0f;
    bpk[idx] = (__bf16)val;
}

// ---------------------------------------------------------------------------
// Main GEMM — round-0 structure (W[4][8] banked window, 112 VGPR, spill-free,
// 2 waves/SIMD) + m201-style schedule control:
//   * W-bank refills spread 1-per-kt (slot i of bank g4 dies at kt=8g+i,
//     msub 0 — refill placed AFTER that kt's MFMA cluster), giving the
//     fine DS/VMEM/MFMA interleave m196 showed is worth 7-27%
//   * s_setprio(1) around each 8-MFMA cluster (T5: +21-39% on schedules
//     with wave role drift; our K-loop is barrier-free so waves drift)
//   * staging loads issued after group 1 (off the BQ-prime vmcnt window;
//     sreg live range = groups 2..7 only)
// Rounds 1-2 lesson: register-reduction variants (rolling Q, launch_bounds
// 3/4) all spill (~250MB-2.4GB scratch traffic) — this workload needs the
// 4-msub/230-reg operating point; 2 waves/SIMD can still reach 62% MfmaUtil
// (m201) with the right schedule.
// ---------------------------------------------------------------------------
__global__ __launch_bounds__(BLK, 2)
void hoa_bin_gemm(const float* __restrict__ hoa,
                  const __bf16* __restrict__ bpk,
                  float* __restrict__ out)
{
    __shared__ __align__(16) __bf16 xs[2][XS_LEN];

    const int qb   = blockIdx.x;          // 0..117
    const int b    = blockIdx.y;          // 0..7
    const int tid  = threadIdx.x;
    const int lane = tid & 63;
    const int wv   = tid >> 6;            // wave 0..3
    const int mlan = lane & 15;
    const int quad = lane >> 4;

    const int q0 = qb * ROWS;
    const int t0 = 16 * q0 - 2048;        // sample index of xs[.][0]

    const int abase = wv * 1024 + 16 * mlan + 8 * quad;

    const float* xb = hoa + (long)b * N_CH * N_SMP;

    f32x4 acc[4][2] = {};                 // [msub][ear]

    // ---- prologue: stage channel 0 into xs[0] ----
    {
        float4 v[7];
        #pragma unroll
        for (int k = 0; k < 7; ++k) {
            const int i4 = tid + k * BLK;
            const int t  = t0 + 4 * i4;
            float4 w = {0.f, 0.f, 0.f, 0.f};
            if (i4 < NF4 && t >= 0 && t <= N_SMP - 4) w = *(const float4*)(xb + t);
            v[k] = w;
        }
        #pragma unroll
        for (int k = 0; k < 7; ++k) {
            const int i4 = tid + k * BLK;
            if (i4 < NF4) {
                union { __bf16 hh[4]; uint2 u; } pk;
                pk.hh[0] = (__bf16)v[k].x; pk.hh[1] = (__bf16)v[k].y;
                pk.hh[2] = (__bf16)v[k].z; pk.hh[3] = (__bf16)v[k].w;
                *(uint2*)(&xs[0][4 * i4]) = pk.u;
            }
        }
    }

    for (int c = 0; c < N_CH; ++c) {
        const __bf16* bp = bpk + (long)c * (NKT * 1024) + lane * 8;

        // ---- prime B queue (depth 3) before barrier: L2 latency hides
        //      under the barrier wait; no LDS dependency ----
        bf16x8 BQ0[3], BQ1[3];
        #pragma unroll
        for (int d = 0; d < 3; ++d) {
            BQ0[d] = *(const bf16x8*)(bp + d * 1024);
            BQ1[d] = *(const bf16x8*)(bp + d * 1024 + 512);
        }

        __syncthreads();   // xs[c&1] staged; previous readers done

        const __bf16* xw = &xs[c & 1][0];

        // ---- preload A window: bank s holds f(8s..8s+7) ----
        bf16x8 W[4][8];
        #pragma unroll
        for (int s = 0; s < 4; ++s)
            #pragma unroll
            for (int i = 0; i < 8; ++i)
                W[s][i] = *(const bf16x8*)(xw + abase + 32 * (8 * s + i));

        float4 sreg[7];    // staging regs — live groups 2..7 only

        // ---- 8 groups of 8 K-tiles; per-kt: {BQ refill, MFMA x8, W refill} ----
        #pragma unroll
        for (int g = 0; g < 8; ++g) {
            const int g4 = g & 3;
            #pragma unroll
            for (int i = 0; i < 8; ++i) {
                const int kt = 8 * g + i;
                const int d  = kt % 3;
                bf16x8 b0 = BQ0[d];
                bf16x8 b1 = BQ1[d];
                const int ktp = (kt + 3 <= 64) ? kt + 3 : 64;   // compile-time
                BQ0[d] = *(const bf16x8*)(bp + ktp * 1024);
                BQ1[d] = *(const bf16x8*)(bp + ktp * 1024 + 512);
                __builtin_amdgcn_s_setprio(1);
                #pragma unroll
                for (int s = 0; s < 4; ++s) {
                    acc[s][0] = __builtin_amdgcn_mfma_f32_16x16x32_bf16(
                                    W[(g4 + s) & 3][i], b0, acc[s][0], 0, 0, 0);
                    acc[s][1] = __builtin_amdgcn_mfma_f32_16x16x32_bf16(
                                    W[(g4 + s) & 3][i], b1, acc[s][1], 0, 0, 0);
                }
                __builtin_amdgcn_s_setprio(0);
                // refill slot i of retiring bank g4 with f(8g+32+i)
                // (dead after msub 0 used it this kt; g=7 refill lands in pad)
                W[g4][i] = *(const bf16x8*)(xw + abase + 32 * (8 * g + 32 + i));
            }
            // issue next-channel staging loads after group 1: off the
            // BQ-prime vmcnt window, ~6 groups of MFMA cover HBM latency
            if (g == 1 && c + 1 < N_CH) {
                const float* xc = xb + (long)(c + 1) * N_SMP;
                #pragma unroll
                for (int k = 0; k < 7; ++k) {
                    const int i4 = tid + k * BLK;
                    const int t  = t0 + 4 * i4;
                    float4 w = {0.f, 0.f, 0.f, 0.f};
                    if (i4 < NF4 && t >= 0 && t <= N_SMP - 4) w = *(const float4*)(xc + t);
                    sreg[k] = w;
                }
            }
        }

        // ---- tail kt = 64: bank s slot 0 holds f(64+8s); BQ slot 64%3 = 1 ----
        {
            bf16x8 b0 = BQ0[1];
            bf16x8 b1 = BQ1[1];
            __builtin_amdgcn_s_setprio(1);
            #pragma unroll
            for (int s = 0; s < 4; ++s) {
                acc[s][0] = __builtin_amdgcn_mfma_f32_16x16x32_bf16(
                                W[s][0], b0, acc[s][0], 0, 0, 0);
                acc[s][1] = __builtin_amdgcn_mfma_f32_16x16x32_bf16(
                                W[s][0], b1, acc[s][1], 0, 0, 0);
            }
            __builtin_amdgcn_s_setprio(0);
        }

        // ---- write staged channel c+1 into the other buffer ----
        if (c + 1 < N_CH) {
            __bf16* xd = &xs[(c + 1) & 1][0];
            #pragma unroll
            for (int k = 0; k < 7; ++k) {
                const int i4 = tid + k * BLK;
                if (i4 < NF4) {
                    union { __bf16 hh[4]; uint2 u; } pk;
                    pk.hh[0] = (__bf16)sreg[k].x; pk.hh[1] = (__bf16)sreg[k].y;
                    pk.hh[2] = (__bf16)sreg[k].z; pk.hh[3] = (__bf16)sreg[k].w;
                    *(uint2*)(&xd[4 * i4]) = pk.u;
                }
            }
        }
    }

    // ---- epilogue: C/D layout row = quad*4 + r, col = lane&15 (verified) ----
    const long ob = (long)b * N_EARS * N_SMP;
    #pragma unroll
    for (int s = 0; s < 4; ++s) {
        #pragma unroll
        for (int e = 0; e < N_EARS; ++e) {
            #pragma unroll
            for (int r = 0; r < 4; ++r) {
                const int rl = wv * 64 + s * 16 + quad * 4 + r;
                const int q  = q0 + rl;
                if (q < N_QROWS)
                    out[ob + (long)e * N_SMP + 16 * q + mlan] = acc[s][e][r];
            }
        }
    }
}

// ---------------------------------------------------------------------------
extern "C" void kernel_launch(void* const* d_in, const int* in_sizes, int n_in,
                              void* d_out, int out_size, void* d_ws, size_t ws_size,
                              hipStream_t stream)
{
    const float* hoa = (const float*)d_in[0];   // [8,16,480000] fp32
    const float* h   = (const float*)d_in[1];   // [2,16,2048]  fp32
    float* out       = (float*)d_out;           // [8,2,480000] fp32
    __bf16* bpk      = (__bf16*)d_ws;           // 2,129,920 B filter pack

    const int total_bpk = N_CH * NKT * 2 * 64 * 8;          // 1,064,960
    build_bpk<<<(total_bpk + 255) / 256, 256, 0, stream>>>(h, bpk);

    dim3 grid(QB_PER_B, N_BATCH);
    hoa_bin_gemm<<<grid, BLK, 0, stream>>>(hoa, bpk, out);
}